// Round 1
// baseline (128.827 us; speedup 1.0000x reference)
//
#include <hip/hip_runtime.h>
#include <hip/hip_bf16.h>

// SelfAttentionLayer: B=64, N=1024, C=128, D=64
// R5 (this round):
//  (a) attn_kernel: __launch_bounds__(256,2) + register-pressure restructure
//      (per-s exp fusion: sc live 32->16; bvf split bv0/bv1 with staggered
//      issue). Guarantees <=256 VGPR -> 2 blocks/CU so the K-prefetch /
//      V-early-issue latency hiding actually has a co-resident wave.
//  (b) qkv_kernel: block->(batch,tile) remap so batch%8 == blockIdx%8 ==
//      dispatch XCD. Producer XCD == consumer XCD (attn uses b=blk&63, same
//      residue) -> K/V/qs stay in the local 4MB L2 (2MB K/V + 1MB qs per
//      XCD fits) instead of bouncing through L3.
// R4 design retained: frag-major K/V layouts, barrier-free attn, 1KB
// coalesced B-frag loads, K register double-buffer.

#define Bsz 64
#define Nsz 1024
#define Csz 128
#define Dsz 64

typedef __attribute__((ext_vector_type(8))) short short8;
typedef __attribute__((ext_vector_type(4))) float f32x4;

__device__ __forceinline__ unsigned short f2bf(float f) {
    union { float f; unsigned u; } v; v.f = f;
    unsigned r = v.u + 0x7FFF + ((v.u >> 16) & 1);
    return (unsigned short)(r >> 16);
}
__device__ __forceinline__ float bf2f(unsigned short h) {
    union { unsigned u; float f; } v; v.u = ((unsigned)h) << 16;
    return v.f;
}
__device__ __forceinline__ unsigned pack_bf16rn(float lo, float hi) {
    unsigned ulo = __float_as_uint(lo) + 0x8000u;
    unsigned uhi = __float_as_uint(hi) + 0x8000u;
    return __builtin_amdgcn_perm(uhi, ulo, 0x07060302u);
}

#define SCq (0.125f * 1.44269504f)     // 1/sqrt(D) * log2(e) folded into qs
#define INV_SC (1.0f / (0.125f * 1.44269504f))

// ---------------- Kernel 0: weight prep -> B-frag layout bf16 ----------------
__global__ __launch_bounds__(256) void wprep_kernel(
    const float* __restrict__ Wq, const float* __restrict__ Wk,
    const float* __restrict__ Wv, unsigned short* __restrict__ wfrag)
{
    int t = blockIdx.x * 256 + threadIdx.x;   // 0..1023 = (dt,ksi,lane)
    int lane = t & 63, ksi = (t >> 6) & 3, dt = t >> 8;
    int l16 = lane & 15, quad = lane >> 4;
    int d = dt * 16 + l16;
    int c0 = ksi * 32 + quad * 8;
    short8 h8, l8, k8, v8;
    #pragma unroll
    for (int j = 0; j < 8; j++) {
        float w = Wq[(c0 + j) * Dsz + d];
        unsigned short h = f2bf(w);
        h8[j] = (short)h;
        l8[j] = (short)f2bf(w - bf2f(h));
        k8[j] = (short)f2bf(Wk[(c0 + j) * Dsz + d]);
        v8[j] = (short)f2bf(Wv[(c0 + j) * Dsz + d]);
    }
    int idx = (dt * 4 + ksi) * 64 + lane;
    ((short8*)wfrag)[0 * 1024 + idx] = h8;
    ((short8*)wfrag)[1 * 1024 + idx] = l8;
    ((short8*)wfrag)[2 * 1024 + idx] = k8;
    ((short8*)wfrag)[3 * 1024 + idx] = v8;
}

// ---------------- Kernel A: QKV projection via MFMA ----------------
// grid 1024 x 256; block = 64 rows; wave = d-tile dt.
// Block remap: r8 = blk&7 (XCD), batch = r8 + 8*(m>>4), tile = m&15 so that
// batch%8 == blk%8 -> K/V/qs for batch b are written from (and cached in)
// the same XCD's L2 that attn's blocks for batch b will run on.
__global__ __launch_bounds__(256) void qkv_kernel(
    const float* __restrict__ x, const unsigned short* __restrict__ wfrag,
    const float* __restrict__ bq, const float* __restrict__ bk,
    const float* __restrict__ bv,
    unsigned short* __restrict__ qs, unsigned short* __restrict__ ks2,
    unsigned short* __restrict__ vt2)
{
    __shared__ short xh[8192];   // [4 rt][4 ks][64 lane][8] A-frag layout
    __shared__ short xl[8192];
    const int t    = threadIdx.x;
    const int lane = t & 63;
    const int l16  = lane & 15, quad = lane >> 4;
    const int dt   = t >> 6;
    // XCD-affine remap (bijective): blk -> (batch, tile) with batch%8==blk%8
    const int blk = blockIdx.x;
    const int r8  = blk & 7;
    const int m   = blk >> 3;                  // 0..127
    const int bat = r8 + 8 * (m >> 4);         // 0..63
    const int til = m & 15;                    // 0..15
    const long rowbase = ((long)bat * 16 + til) * 64;
    const int d = dt * 16 + l16;

    // weight B-frags: 16 coalesced b128 loads (L2-hot wfrag)
    short8 wqh[4], wql[4], wkf[4], wvf[4];
    #pragma unroll
    for (int ksi = 0; ksi < 4; ksi++) {
        int idx = (dt * 4 + ksi) * 64 + lane;
        wqh[ksi] = ((const short8*)wfrag)[0 * 1024 + idx];
        wql[ksi] = ((const short8*)wfrag)[1 * 1024 + idx];
        wkf[ksi] = ((const short8*)wfrag)[2 * 1024 + idx];
        wvf[ksi] = ((const short8*)wfrag)[3 * 1024 + idx];
    }

    // stage x -> bf16 hi/lo in A-frag layout
    {
        const int row = t & 63;
        const float* xrow = x + (rowbase + row) * Csz;
        #pragma unroll
        for (int p = 0; p < 4; p++) {
            int cb = (t >> 6) + p * 4;
            float4 a = *(const float4*)(xrow + cb * 8);
            float4 bb = *(const float4*)(xrow + cb * 8 + 4);
            float f[8] = {a.x, a.y, a.z, a.w, bb.x, bb.y, bb.z, bb.w};
            short8 hi, lo;
            #pragma unroll
            for (int i = 0; i < 8; i++) {
                unsigned short h = f2bf(f[i]);
                hi[i] = (short)h;
                lo[i] = (short)f2bf(f[i] - bf2f(h));
            }
            int unit = ((row >> 4) * 4 + (cb >> 2)) * 64 + ((row & 15) | ((cb & 3) << 4));
            *(short8*)&xh[unit * 8] = hi;
            *(short8*)&xl[unit * 8] = lo;
        }
    }
    __syncthreads();

    f32x4 aq[4], ak[4], av[4];
    #pragma unroll
    for (int i = 0; i < 4; i++) {
        aq[i] = (f32x4){0.f, 0.f, 0.f, 0.f};
        ak[i] = (f32x4){0.f, 0.f, 0.f, 0.f};
        av[i] = (f32x4){0.f, 0.f, 0.f, 0.f};
    }
    #pragma unroll
    for (int ksi = 0; ksi < 4; ksi++) {
        #pragma unroll
        for (int rt = 0; rt < 4; rt++) {
            short8 ah = *(const short8*)&xh[((rt * 4 + ksi) * 64 + lane) * 8];
            short8 al = *(const short8*)&xl[((rt * 4 + ksi) * 64 + lane) * 8];
            aq[rt] = __builtin_amdgcn_mfma_f32_16x16x32_bf16(ah, wqh[ksi], aq[rt], 0, 0, 0);
            aq[rt] = __builtin_amdgcn_mfma_f32_16x16x32_bf16(al, wqh[ksi], aq[rt], 0, 0, 0);
            aq[rt] = __builtin_amdgcn_mfma_f32_16x16x32_bf16(ah, wql[ksi], aq[rt], 0, 0, 0);
            ak[rt] = __builtin_amdgcn_mfma_f32_16x16x32_bf16(ah, wkf[ksi], ak[rt], 0, 0, 0);
            av[rt] = __builtin_amdgcn_mfma_f32_16x16x32_bf16(ah, wvf[ksi], av[rt], 0, 0, 0);
        }
    }

    // ---- epilogue ----
    const float bqd = bq[d], bkd = bk[d], bvd = bv[d];
    const long b  = rowbase >> 10;
    const int  kt = (int)((rowbase >> 6) & 15);

    // K frag-scatter constants: value(n,d) -> frag (kb=rt, half, lane=quadk*16+quad*4+r, j)
    const int half  = dt >> 1;
    const int quadk = ((dt & 1) << 1) | (l16 >> 3);
    const int jk    = l16 & 7;
    unsigned short* kbase = ks2 + ((((long)(b * 16 + kt) * 4) * 2 + half) * 64) * 8;

    float vv[4][4];   // [r][rt]
    #pragma unroll
    for (int rt = 0; rt < 4; rt++) {
        #pragma unroll
        for (int r = 0; r < 4; r++) {
            long n = rowbase + rt * 16 + quad * 4 + r;
            float q = fmaxf(aq[rt][r] + bqd, 0.f);
            float k = fmaxf(ak[rt][r] + bkd, 0.f);
            vv[r][rt] = fmaxf(av[rt][r] + bvd, 0.f);
            qs[n * Dsz + d] = f2bf(q * SCq);
            kbase[((long)rt * 2 * 64 + quadk * 16 + quad * 4 + r) * 8 + jk] = f2bf(k);
        }
    }
    // V frag-major stores: 2 x b128. lane slot = quadp*16 + l16, shorts j=r*4+rt (mod 8)
    const int ck = quad >> 1;
    const int quadp = (quad & 1) * 2;
    long vidx = (((long)(b * 16 + kt) * 4 + dt) * 2 + ck) * 64 + quadp * 16 + l16;
    uint4 o0 = make_uint4(pack_bf16rn(vv[0][0], vv[0][1]), pack_bf16rn(vv[0][2], vv[0][3]),
                          pack_bf16rn(vv[1][0], vv[1][1]), pack_bf16rn(vv[1][2], vv[1][3]));
    uint4 o1 = make_uint4(pack_bf16rn(vv[2][0], vv[2][1]), pack_bf16rn(vv[2][2], vv[2][3]),
                          pack_bf16rn(vv[3][0], vv[3][1]), pack_bf16rn(vv[3][2], vv[3][3]));
    ((uint4*)vt2)[vidx]      = o0;
    ((uint4*)vt2)[vidx + 16] = o1;
}

// ---------------- Kernel B: barrier-free flash attention ----------------
// grid 512: b = blk&63 (XCD L2 affinity), qh = blk>>6. 4 waves x 32 q.
// __launch_bounds__(256,2): cap VGPR <=256 so 2 blocks/CU co-reside.
// Register-lean schedule per kt:
//   issue bv0 -> QK(s=0) -> issue bv1 -> exp(s=0) -> QK(s=1) ->
//   issue kf-prefetch -> exp(s=1) -> PV(ck=0,bv0) -> PV(ck=1,bv1)
__global__ __launch_bounds__(256, 2) void attn_kernel(
    const unsigned short* __restrict__ qs,
    const unsigned short* __restrict__ ks2,
    const unsigned short* __restrict__ vt2,
    float* __restrict__ out)
{
    __shared__ short Pl[4][32][72];    // per-wave P (C->A layout round-trip)

    const int t    = threadIdx.x;
    const int wave = t >> 6;
    const int lane = t & 63;
    const int l16  = lane & 15;
    const int quad = lane >> 4;
    const int b    = blockIdx.x & 63;
    const int qh   = blockIdx.x >> 6;
    const int qbase = qh * 128 + wave * 32;

    const short8* ks8 = (const short8*)ks2 + (long)b * (16 * 4 * 2 * 64);
    const short8* vt8 = (const short8*)vt2 + (long)b * (16 * 4 * 2 * 64);

    // Q A-frags
    short8 aq[2][2];
    #pragma unroll
    for (int s = 0; s < 2; s++) {
        const unsigned short* qp = qs + ((long)b * Nsz + qbase + s * 16 + l16) * Dsz + quad * 8;
        aq[s][0] = *(const short8*)(qp);
        aq[s][1] = *(const short8*)(qp + 32);
    }

    f32x4 O[2][4];
    float lsum[2][4];
    #pragma unroll
    for (int s = 0; s < 2; s++)
        #pragma unroll
        for (int i = 0; i < 4; i++) { O[s][i] = (f32x4){0.f,0.f,0.f,0.f}; lsum[s][i] = 0.f; }

    // preload K-frags for kt=0: frag idx (kb*2+half)*64 + lane
    short8 kf[4][2];
    #pragma unroll
    for (int kb = 0; kb < 4; kb++) {
        kf[kb][0] = ks8[(kb * 2 + 0) * 64 + lane];
        kf[kb][1] = ks8[(kb * 2 + 1) * 64 + lane];
    }

    for (int kt = 0; kt < 16; kt++) {
        // V frags ck=0 — issued first, consumed at PV(ck=0)
        short8 bv0[4], bv1[4];
        #pragma unroll
        for (int cb = 0; cb < 4; cb++)
            bv0[cb] = vt8[((long)kt * 8 + cb * 2 + 0) * 64 + lane];

        // S = q K^T, strip s=0
        f32x4 sc0[4];
        #pragma unroll
        for (int kb = 0; kb < 4; kb++) {
            f32x4 z = (f32x4){0.f, 0.f, 0.f, 0.f};
            z = __builtin_amdgcn_mfma_f32_16x16x32_bf16(aq[0][0], kf[kb][0], z, 0, 0, 0);
            z = __builtin_amdgcn_mfma_f32_16x16x32_bf16(aq[0][1], kf[kb][1], z, 0, 0, 0);
            sc0[kb] = z;
        }

        // V frags ck=1 — flies under exp(s=0)+QK(s=1)
        #pragma unroll
        for (int cb = 0; cb < 4; cb++)
            bv1[cb] = vt8[((long)kt * 8 + cb * 2 + 1) * 64 + lane];

        // P = 2^S for s=0, pack into Pl (frees sc0 before QK s=1)
        #pragma unroll
        for (int r = 0; r < 4; r++) {
            float p0 = __builtin_amdgcn_exp2f(sc0[0][r]);
            float p1 = __builtin_amdgcn_exp2f(sc0[1][r]);
            float p2 = __builtin_amdgcn_exp2f(sc0[2][r]);
            float p3 = __builtin_amdgcn_exp2f(sc0[3][r]);
            lsum[0][r] += (p0 + p1) + (p2 + p3);
            *(uint2*)&Pl[wave][quad * 4 + r][l16 * 4] =
                make_uint2(pack_bf16rn(p0, p1), pack_bf16rn(p2, p3));
        }

        // S = q K^T, strip s=1
        f32x4 sc1[4];
        #pragma unroll
        for (int kb = 0; kb < 4; kb++) {
            f32x4 z = (f32x4){0.f, 0.f, 0.f, 0.f};
            z = __builtin_amdgcn_mfma_f32_16x16x32_bf16(aq[1][0], kf[kb][0], z, 0, 0, 0);
            z = __builtin_amdgcn_mfma_f32_16x16x32_bf16(aq[1][1], kf[kb][1], z, 0, 0, 0);
            sc1[kb] = z;
        }

        // prefetch next kt's K-frags (kf dead here; flies under exp+PV)
        short8 kf2[4][2];
        {
            int ktn = (kt + 1) & 15;
            #pragma unroll
            for (int kb = 0; kb < 4; kb++) {
                kf2[kb][0] = ks8[((long)ktn * 8 + kb * 2 + 0) * 64 + lane];
                kf2[kb][1] = ks8[((long)ktn * 8 + kb * 2 + 1) * 64 + lane];
            }
        }

        // P = 2^S for s=1
        #pragma unroll
        for (int r = 0; r < 4; r++) {
            float p0 = __builtin_amdgcn_exp2f(sc1[0][r]);
            float p1 = __builtin_amdgcn_exp2f(sc1[1][r]);
            float p2 = __builtin_amdgcn_exp2f(sc1[2][r]);
            float p3 = __builtin_amdgcn_exp2f(sc1[3][r]);
            lsum[1][r] += (p0 + p1) + (p2 + p3);
            *(uint2*)&Pl[wave][16 + quad * 4 + r][l16 * 4] =
                make_uint2(pack_bf16rn(p0, p1), pack_bf16rn(p2, p3));
        }

        // O += P V  (within-wave Pl read in A-layout; lgkmcnt only, no barrier)
        #pragma unroll
        for (int s = 0; s < 2; s++) {
            short8 ap = *(const short8*)&Pl[wave][s * 16 + l16][quad * 8];
            #pragma unroll
            for (int cb = 0; cb < 4; cb++)
                O[s][cb] = __builtin_amdgcn_mfma_f32_16x16x32_bf16(ap, bv0[cb], O[s][cb], 0, 0, 0);
        }
        #pragma unroll
        for (int s = 0; s < 2; s++) {
            short8 ap = *(const short8*)&Pl[wave][s * 16 + l16][32 + quad * 8];
            #pragma unroll
            for (int cb = 0; cb < 4; cb++)
                O[s][cb] = __builtin_amdgcn_mfma_f32_16x16x32_bf16(ap, bv1[cb], O[s][cb], 0, 0, 0);
        }

        #pragma unroll
        for (int kb = 0; kb < 4; kb++) { kf[kb][0] = kf2[kb][0]; kf[kb][1] = kf2[kb][1]; }
    }

    // deferred row-sum reduction (lanes sharing a row: same quad, l16 0..15)
    #pragma unroll
    for (int s = 0; s < 2; s++)
        #pragma unroll
        for (int r = 0; r < 4; r++)
            #pragma unroll
            for (int off = 1; off < 16; off <<= 1)
                lsum[s][r] += __shfl_xor(lsum[s][r], off);

    // epilogue: out = O/l + q (q from bf16 scaled copy)
    #pragma unroll
    for (int s = 0; s < 2; s++) {
        #pragma unroll
        for (int r = 0; r < 4; r++) {
            float rl = 1.0f / lsum[s][r];
            long nrow = (long)b * Nsz + qbase + s * 16 + quad * 4 + r;
            #pragma unroll
            for (int cb = 0; cb < 4; cb++) {
                int d = cb * 16 + l16;
                float qv = bf2f(qs[nrow * Dsz + d]) * INV_SC;
                out[nrow * Dsz + d] = O[s][cb][r] * rl + qv;
            }
        }
    }
}

extern "C" void kernel_launch(void* const* d_in, const int* in_sizes, int n_in,
                              void* d_out, int out_size, void* d_ws, size_t ws_size,
                              hipStream_t stream) {
    const float* x  = (const float*)d_in[0];
    const float* Wq = (const float*)d_in[1];
    const float* bq = (const float*)d_in[2];
    const float* Wk = (const float*)d_in[3];
    const float* bk = (const float*)d_in[4];
    const float* Wv = (const float*)d_in[5];
    const float* bv = (const float*)d_in[6];
    float* out = (float*)d_out;

    char* ws = (char*)d_ws;
    unsigned short* qsc   = (unsigned short*)ws;                 // 8 MB bf16 q*SC, [n][d]
    unsigned short* ks2   = (unsigned short*)(ws + 0x1000000);   // 8 MB bf16 K frag-major
    unsigned short* vt2   = (unsigned short*)(ws + 0x2000000);   // 8 MB bf16 V^T frag-major
    unsigned short* wfrag = (unsigned short*)(ws + 0x3000000);   // 64 KB W frags

    wprep_kernel<<<dim3(4), dim3(256), 0, stream>>>(Wq, Wk, Wv, wfrag);
    qkv_kernel<<<dim3(1024), dim3(256), 0, stream>>>(
        x, wfrag, bq, bk, bv, qsc, ks2, vt2);
    attn_kernel<<<dim3(512), dim3(256), 0, stream>>>(
        qsc, ks2, vt2, out);
}

// Round 3
// 122.826 us; speedup vs baseline: 1.0489x; 1.0489x over previous
//
#include <hip/hip_runtime.h>
#include <hip/hip_bf16.h>

// SelfAttentionLayer: B=64, N=1024, C=128, D=64
// R7: exact R4 structure (3 kernels, 120.7us measured) with ONE isolated
// change: qkv block->(batch,tile) remap so batch%8 == blockIdx%8. attn's
// block (qh*64+b) sits on XCD b%8; with this remap the producer of batch
// b's K/V/qs is also XCD b%8, and the per-XCD attn working set (8 batches
// x 384KB = 3MB) fits the 4MB local L2. R4's mapping spread each batch's
// tiles over all 8 XCDs -> 7/8 of attn's 512MB K/V stream was remote.
// R5 bundled this remap with an attn restructure (regressed); R6's fusion
// broke cross-XCD visibility. This isolates the remap on the proven base.

#define Bsz 64
#define Nsz 1024
#define Csz 128
#define Dsz 64

typedef __attribute__((ext_vector_type(8))) short short8;
typedef __attribute__((ext_vector_type(4))) float f32x4;

__device__ __forceinline__ unsigned short f2bf(float f) {
    union { float f; unsigned u; } v; v.f = f;
    unsigned r = v.u + 0x7FFF + ((v.u >> 16) & 1);
    return (unsigned short)(r >> 16);
}
__device__ __forceinline__ float bf2f(unsigned short h) {
    union { unsigned u; float f; } v; v.u = ((unsigned)h) << 16;
    return v.f;
}
__device__ __forceinline__ unsigned pack_bf16rn(float lo, float hi) {
    unsigned ulo = __float_as_uint(lo) + 0x8000u;
    unsigned uhi = __float_as_uint(hi) + 0x8000u;
    return __builtin_amdgcn_perm(uhi, ulo, 0x07060302u);
}

#define SCq (0.125f * 1.44269504f)     // 1/sqrt(D) * log2(e) folded into qs
#define INV_SC (1.0f / (0.125f * 1.44269504f))

// ---------------- Kernel 0: weight prep -> B-frag layout bf16 ----------------
__global__ __launch_bounds__(256) void wprep_kernel(
    const float* __restrict__ Wq, const float* __restrict__ Wk,
    const float* __restrict__ Wv, unsigned short* __restrict__ wfrag)
{
    int t = blockIdx.x * 256 + threadIdx.x;   // 0..1023 = (dt,ksi,lane)
    int lane = t & 63, ksi = (t >> 6) & 3, dt = t >> 8;
    int l16 = lane & 15, quad = lane >> 4;
    int d = dt * 16 + l16;
    int c0 = ksi * 32 + quad * 8;
    short8 h8, l8, k8, v8;
    #pragma unroll
    for (int j = 0; j < 8; j++) {
        float w = Wq[(c0 + j) * Dsz + d];
        unsigned short h = f2bf(w);
        h8[j] = (short)h;
        l8[j] = (short)f2bf(w - bf2f(h));
        k8[j] = (short)f2bf(Wk[(c0 + j) * Dsz + d]);
        v8[j] = (short)f2bf(Wv[(c0 + j) * Dsz + d]);
    }
    int idx = (dt * 4 + ksi) * 64 + lane;
    ((short8*)wfrag)[0 * 1024 + idx] = h8;
    ((short8*)wfrag)[1 * 1024 + idx] = l8;
    ((short8*)wfrag)[2 * 1024 + idx] = k8;
    ((short8*)wfrag)[3 * 1024 + idx] = v8;
}

// ---------------- Kernel A: QKV projection via MFMA ----------------
// grid 1024 x 256; block = 64 rows; wave = d-tile dt.
// XCD-affine remap (bijective, R5-verified): blk -> (batch, tile) with
// batch%8 == blk%8 == dispatch XCD -> K/V/qs for batch b are written from
// (and stay cached in) the same XCD's L2 that attn's batch-b blocks run on.
__global__ __launch_bounds__(256) void qkv_kernel(
    const float* __restrict__ x, const unsigned short* __restrict__ wfrag,
    const float* __restrict__ bq, const float* __restrict__ bk,
    const float* __restrict__ bv,
    unsigned short* __restrict__ qs, unsigned short* __restrict__ ks2,
    unsigned short* __restrict__ vt2)
{
    __shared__ short xh[8192];   // [4 rt][4 ks][64 lane][8] A-frag layout
    __shared__ short xl[8192];
    const int t    = threadIdx.x;
    const int lane = t & 63;
    const int l16  = lane & 15, quad = lane >> 4;
    const int dt   = t >> 6;
    // remap: r8 = XCD residue, bat in 0..63 with bat%8==r8, til in 0..15
    const int blk = blockIdx.x;
    const int r8  = blk & 7;
    const int m   = blk >> 3;                  // 0..127
    const int bat = r8 + 8 * (m >> 4);         // 0..63
    const int til = m & 15;                    // 0..15
    const long rowbase = ((long)bat * 16 + til) * 64;
    const int d = dt * 16 + l16;

    // weight B-frags: 16 coalesced b128 loads (L2-hot wfrag)
    short8 wqh[4], wql[4], wkf[4], wvf[4];
    #pragma unroll
    for (int ksi = 0; ksi < 4; ksi++) {
        int idx = (dt * 4 + ksi) * 64 + lane;
        wqh[ksi] = ((const short8*)wfrag)[0 * 1024 + idx];
        wql[ksi] = ((const short8*)wfrag)[1 * 1024 + idx];
        wkf[ksi] = ((const short8*)wfrag)[2 * 1024 + idx];
        wvf[ksi] = ((const short8*)wfrag)[3 * 1024 + idx];
    }

    // stage x -> bf16 hi/lo in A-frag layout
    {
        const int row = t & 63;
        const float* xrow = x + (rowbase + row) * Csz;
        #pragma unroll
        for (int p = 0; p < 4; p++) {
            int cb = (t >> 6) + p * 4;
            float4 a = *(const float4*)(xrow + cb * 8);
            float4 bb = *(const float4*)(xrow + cb * 8 + 4);
            float f[8] = {a.x, a.y, a.z, a.w, bb.x, bb.y, bb.z, bb.w};
            short8 hi, lo;
            #pragma unroll
            for (int i = 0; i < 8; i++) {
                unsigned short h = f2bf(f[i]);
                hi[i] = (short)h;
                lo[i] = (short)f2bf(f[i] - bf2f(h));
            }
            int unit = ((row >> 4) * 4 + (cb >> 2)) * 64 + ((row & 15) | ((cb & 3) << 4));
            *(short8*)&xh[unit * 8] = hi;
            *(short8*)&xl[unit * 8] = lo;
        }
    }
    __syncthreads();

    f32x4 aq[4], ak[4], av[4];
    #pragma unroll
    for (int i = 0; i < 4; i++) {
        aq[i] = (f32x4){0.f, 0.f, 0.f, 0.f};
        ak[i] = (f32x4){0.f, 0.f, 0.f, 0.f};
        av[i] = (f32x4){0.f, 0.f, 0.f, 0.f};
    }
    #pragma unroll
    for (int ksi = 0; ksi < 4; ksi++) {
        #pragma unroll
        for (int rt = 0; rt < 4; rt++) {
            short8 ah = *(const short8*)&xh[((rt * 4 + ksi) * 64 + lane) * 8];
            short8 al = *(const short8*)&xl[((rt * 4 + ksi) * 64 + lane) * 8];
            aq[rt] = __builtin_amdgcn_mfma_f32_16x16x32_bf16(ah, wqh[ksi], aq[rt], 0, 0, 0);
            aq[rt] = __builtin_amdgcn_mfma_f32_16x16x32_bf16(al, wqh[ksi], aq[rt], 0, 0, 0);
            aq[rt] = __builtin_amdgcn_mfma_f32_16x16x32_bf16(ah, wql[ksi], aq[rt], 0, 0, 0);
            ak[rt] = __builtin_amdgcn_mfma_f32_16x16x32_bf16(ah, wkf[ksi], ak[rt], 0, 0, 0);
            av[rt] = __builtin_amdgcn_mfma_f32_16x16x32_bf16(ah, wvf[ksi], av[rt], 0, 0, 0);
        }
    }

    // ---- epilogue ----
    const float bqd = bq[d], bkd = bk[d], bvd = bv[d];
    const long b  = rowbase >> 10;
    const int  kt = (int)((rowbase >> 6) & 15);

    // K frag-scatter constants: value(n,d) -> frag (kb=rt, half, lane=quadk*16+quad*4+r, j)
    const int half  = dt >> 1;
    const int quadk = ((dt & 1) << 1) | (l16 >> 3);
    const int jk    = l16 & 7;
    unsigned short* kbase = ks2 + ((((long)(b * 16 + kt) * 4) * 2 + half) * 64) * 8;

    float vv[4][4];   // [r][rt]
    #pragma unroll
    for (int rt = 0; rt < 4; rt++) {
        #pragma unroll
        for (int r = 0; r < 4; r++) {
            long n = rowbase + rt * 16 + quad * 4 + r;
            float q = fmaxf(aq[rt][r] + bqd, 0.f);
            float k = fmaxf(ak[rt][r] + bkd, 0.f);
            vv[r][rt] = fmaxf(av[rt][r] + bvd, 0.f);
            qs[n * Dsz + d] = f2bf(q * SCq);
            kbase[((long)rt * 2 * 64 + quadk * 16 + quad * 4 + r) * 8 + jk] = f2bf(k);
        }
    }
    // V frag-major stores: 2 x b128. lane slot = quadp*16 + l16, shorts j=r*4+rt (mod 8)
    const int ck = quad >> 1;
    const int quadp = (quad & 1) * 2;
    long vidx = (((long)(b * 16 + kt) * 4 + dt) * 2 + ck) * 64 + quadp * 16 + l16;
    uint4 o0 = make_uint4(pack_bf16rn(vv[0][0], vv[0][1]), pack_bf16rn(vv[0][2], vv[0][3]),
                          pack_bf16rn(vv[1][0], vv[1][1]), pack_bf16rn(vv[1][2], vv[1][3]));
    uint4 o1 = make_uint4(pack_bf16rn(vv[2][0], vv[2][1]), pack_bf16rn(vv[2][2], vv[2][3]),
                          pack_bf16rn(vv[3][0], vv[3][1]), pack_bf16rn(vv[3][2], vv[3][3]));
    ((uint4*)vt2)[vidx]      = o0;
    ((uint4*)vt2)[vidx + 16] = o1;
}

// ---------------- Kernel B: barrier-free flash attention ----------------
// grid 512: b = blk&63 (XCD L2 affinity), qh = blk>>6. 4 waves x 32 q.
// All K/V frag loads are coalesced 1KB b128s from frag-major layouts.
__global__ __launch_bounds__(256) void attn_kernel(
    const unsigned short* __restrict__ qs,
    const unsigned short* __restrict__ ks2,
    const unsigned short* __restrict__ vt2,
    float* __restrict__ out)
{
    __shared__ short Pl[4][32][72];    // per-wave P (C->A layout round-trip)

    const int t    = threadIdx.x;
    const int wave = t >> 6;
    const int lane = t & 63;
    const int l16  = lane & 15;
    const int quad = lane >> 4;
    const int b    = blockIdx.x & 63;
    const int qh   = blockIdx.x >> 6;
    const int qbase = qh * 128 + wave * 32;

    const short8* ks8 = (const short8*)ks2 + (long)b * (16 * 4 * 2 * 64);
    const short8* vt8 = (const short8*)vt2 + (long)b * (16 * 4 * 2 * 64);

    // Q A-frags
    short8 aq[2][2];
    #pragma unroll
    for (int s = 0; s < 2; s++) {
        const unsigned short* qp = qs + ((long)b * Nsz + qbase + s * 16 + l16) * Dsz + quad * 8;
        aq[s][0] = *(const short8*)(qp);
        aq[s][1] = *(const short8*)(qp + 32);
    }

    f32x4 O[2][4];
    float lsum[2][4];
    #pragma unroll
    for (int s = 0; s < 2; s++)
        #pragma unroll
        for (int i = 0; i < 4; i++) { O[s][i] = (f32x4){0.f,0.f,0.f,0.f}; lsum[s][i] = 0.f; }

    // preload K-frags for kt=0: frag idx (kb*2+half)*64 + lane
    short8 kf[4][2];
    #pragma unroll
    for (int kb = 0; kb < 4; kb++) {
        kf[kb][0] = ks8[(kb * 2 + 0) * 64 + lane];
        kf[kb][1] = ks8[(kb * 2 + 1) * 64 + lane];
    }

    for (int kt = 0; kt < 16; kt++) {
        // V frags for this kt — issued first, consumed ~400 cyc later at PV
        short8 bvf[2][4];
        #pragma unroll
        for (int cb = 0; cb < 4; cb++) {
            bvf[0][cb] = vt8[((long)kt * 8 + cb * 2 + 0) * 64 + lane];
            bvf[1][cb] = vt8[((long)kt * 8 + cb * 2 + 1) * 64 + lane];
        }

        // S = q K^T per strip
        f32x4 sc[2][4];
        #pragma unroll
        for (int s = 0; s < 2; s++) {
            #pragma unroll
            for (int kb = 0; kb < 4; kb++) {
                f32x4 z = (f32x4){0.f, 0.f, 0.f, 0.f};
                z = __builtin_amdgcn_mfma_f32_16x16x32_bf16(aq[s][0], kf[kb][0], z, 0, 0, 0);
                z = __builtin_amdgcn_mfma_f32_16x16x32_bf16(aq[s][1], kf[kb][1], z, 0, 0, 0);
                sc[s][kb] = z;
            }
        }

        // prefetch next kt's K-frags (independent; flies under exp+PV)
        short8 kf2[4][2];
        {
            int ktn = (kt + 1) & 15;
            #pragma unroll
            for (int kb = 0; kb < 4; kb++) {
                kf2[kb][0] = ks8[((long)ktn * 8 + kb * 2 + 0) * 64 + lane];
                kf2[kb][1] = ks8[((long)ktn * 8 + kb * 2 + 1) * 64 + lane];
            }
        }

        // P = 2^S, pi-packed b64 into per-wave Pl
        #pragma unroll
        for (int s = 0; s < 2; s++) {
            #pragma unroll
            for (int r = 0; r < 4; r++) {
                float p0 = __builtin_amdgcn_exp2f(sc[s][0][r]);
                float p1 = __builtin_amdgcn_exp2f(sc[s][1][r]);
                float p2 = __builtin_amdgcn_exp2f(sc[s][2][r]);
                float p3 = __builtin_amdgcn_exp2f(sc[s][3][r]);
                lsum[s][r] += (p0 + p1) + (p2 + p3);
                *(uint2*)&Pl[wave][s * 16 + quad * 4 + r][l16 * 4] =
                    make_uint2(pack_bf16rn(p0, p1), pack_bf16rn(p2, p3));
            }
        }

        // O += P V (within-wave Pl read in A-layout; lgkmcnt only, no barrier)
        #pragma unroll
        for (int ck = 0; ck < 2; ck++) {
            #pragma unroll
            for (int s = 0; s < 2; s++) {
                short8 ap = *(const short8*)&Pl[wave][s * 16 + l16][ck * 32 + quad * 8];
                #pragma unroll
                for (int cb = 0; cb < 4; cb++) {
                    O[s][cb] = __builtin_amdgcn_mfma_f32_16x16x32_bf16(ap, bvf[ck][cb], O[s][cb], 0, 0, 0);
                }
            }
        }

        #pragma unroll
        for (int kb = 0; kb < 4; kb++) { kf[kb][0] = kf2[kb][0]; kf[kb][1] = kf2[kb][1]; }
    }

    // deferred row-sum reduction (lanes sharing a row: same quad, l16 0..15)
    #pragma unroll
    for (int s = 0; s < 2; s++)
        #pragma unroll
        for (int r = 0; r < 4; r++)
            #pragma unroll
            for (int off = 1; off < 16; off <<= 1)
                lsum[s][r] += __shfl_xor(lsum[s][r], off);

    // epilogue: out = O/l + q (q from bf16 scaled copy)
    #pragma unroll
    for (int s = 0; s < 2; s++) {
        #pragma unroll
        for (int r = 0; r < 4; r++) {
            float rl = 1.0f / lsum[s][r];
            long nrow = (long)b * Nsz + qbase + s * 16 + quad * 4 + r;
            #pragma unroll
            for (int cb = 0; cb < 4; cb++) {
                int d = cb * 16 + l16;
                float qv = bf2f(qs[nrow * Dsz + d]) * INV_SC;
                out[nrow * Dsz + d] = O[s][cb][r] * rl + qv;
            }
        }
    }
}

extern "C" void kernel_launch(void* const* d_in, const int* in_sizes, int n_in,
                              void* d_out, int out_size, void* d_ws, size_t ws_size,
                              hipStream_t stream) {
    const float* x  = (const float*)d_in[0];
    const float* Wq = (const float*)d_in[1];
    const float* bq = (const float*)d_in[2];
    const float* Wk = (const float*)d_in[3];
    const float* bk = (const float*)d_in[4];
    const float* Wv = (const float*)d_in[5];
    const float* bv = (const float*)d_in[6];
    float* out = (float*)d_out;

    char* ws = (char*)d_ws;
    unsigned short* qsc   = (unsigned short*)ws;                 // 8 MB bf16 q*SC, [n][d]
    unsigned short* ks2   = (unsigned short*)(ws + 0x1000000);   // 8 MB bf16 K frag-major
    unsigned short* vt2   = (unsigned short*)(ws + 0x2000000);   // 8 MB bf16 V^T frag-major
    unsigned short* wfrag = (unsigned short*)(ws + 0x3000000);   // 64 KB W frags

    wprep_kernel<<<dim3(4), dim3(256), 0, stream>>>(Wq, Wk, Wv, wfrag);
    qkv_kernel<<<dim3(1024), dim3(256), 0, stream>>>(
        x, wfrag, bq, bk, bv, qsc, ks2, vt2);
    attn_kernel<<<dim3(512), dim3(256), 0, stream>>>(
        qsc, ks2, vt2, out);
}